// Round 11
// baseline (132.931 us; speedup 1.0000x reference)
//
#include <hip/hip_runtime.h>
#include <math.h>

// Problem constants (fixed by setup_inputs): B=8, C=4, H=W=64, K=8192
#define N_POINTS 32768   // B*H*W
#define KCODES   8192
#define HW       4096
#define CHW      16384
#define NSEG     64
#define SEGLEN   (KCODES / NSEG)   // 128 codes per segment
#define PPT      8                 // points per thread in vq_scan
#define PTILE    (256 * PPT)       // 2048 points per block

// ws layout (bytes): packed u64[32768] @ 0 — (sortable(best)<<32)|k per point
#define WS_PACKED 0

// Bit-exact conv z = W x + b, numpy sequential c-order, no FMA contraction.
__device__ __forceinline__ void compute_z(
    const float* __restrict__ ze, const float* __restrict__ w,
    const float* __restrict__ bias, int n, float zo[4], float& zz) {
  int b = n >> 12, hw = n & 4095;
  const float* p = ze + b * CHW + hw;
  float x0 = p[0], x1 = p[HW], x2 = p[2 * HW], x3 = p[3 * HW];
#pragma unroll
  for (int o = 0; o < 4; ++o) {
    float acc = __fmul_rn(x0, w[o * 4 + 0]);
    acc = __fadd_rn(acc, __fmul_rn(x1, w[o * 4 + 1]));
    acc = __fadd_rn(acc, __fmul_rn(x2, w[o * 4 + 2]));
    acc = __fadd_rn(acc, __fmul_rn(x3, w[o * 4 + 3]));
    zo[o] = __fadd_rn(acc, bias[o]);
  }
  float s = __fmul_rn(zo[0], zo[0]);
  s = __fadd_rn(s, __fmul_rn(zo[1], zo[1]));
  s = __fadd_rn(s, __fmul_rn(zo[2], zo[2]));
  s = __fadd_rn(s, __fmul_rn(zo[3], zo[3]));
  zz = s;
}

// ---------------- Kernel S: fused staging + conv + argmin scan -------------
// R8 body (best measured: scan 60.4us, absmax 0.0) with two cleanups:
//  (1) chunk loop unrolled 2x as a true ping-pong (A/B buffers alternate) —
//      removes the 20 v_mov/chunk buffer copies (~5% of issue slots);
//  (2) codebook segment staged+transformed in LDS directly from cb (same op
//      order as the old vq_init — bitwise identical), so vq_init is gone.
// Scalar f32 inner loop is the bit-exact floor (~12 VALU ops/pair); packed
// fp32 (R10) and all structural variants (R4-R9) are measured dead ends.
__global__ __launch_bounds__(256, 3) void vq_scan(
    const float* __restrict__ ze, const float* __restrict__ w,
    const float* __restrict__ bias, const float* __restrict__ cb,
    unsigned long long* __restrict__ packed) {
  __shared__ float4 s_c[SEGLEN];            // 2*codebook segment (2048 B)
  __shared__ float  s_n[SEGLEN];            // |c|^2 segment (512 B)
  int tid = threadIdx.x;
  int k0 = blockIdx.y * SEGLEN;
  if (tid < SEGLEN) {
    float4 cv = ((const float4*)cb)[k0 + tid];
    // doubling by 2 is exact: sum(2*z*c) == 2*sum(z*c) bitwise
    s_c[tid] = make_float4(2.f * cv.x, 2.f * cv.y, 2.f * cv.z, 2.f * cv.w);
    float s = __fmul_rn(cv.x, cv.x);
    s = __fadd_rn(s, __fmul_rn(cv.y, cv.y));
    s = __fadd_rn(s, __fmul_rn(cv.z, cv.z));
    s = __fadd_rn(s, __fmul_rn(cv.w, cv.w));
    s_n[tid] = s;
  }
  // conv for this thread's 8 points while the staging loads land
  int n0 = blockIdx.x * PTILE + tid;        // points n0 + 256*p, coalesced
  float z[PPT][4], zz[PPT], best[PPT];
  int bidx[PPT];
#pragma unroll
  for (int p = 0; p < PPT; ++p) {
    compute_z(ze, w, bias, n0 + 256 * p, z[p], zz[p]);
    best[p] = INFINITY;
    bidx[p] = 0;
  }
  __syncthreads();

  // 4-code body: 2*dot with numpy's sequential rounding order, then
  // (|z|^2 - 2*dot) + |c|^2 left-to-right; strict < + ascending k = first-min.
  auto body = [&](const float4 (&cc)[4], const float4& nv, int kbase) {
    float cnr[4] = {nv.x, nv.y, nv.z, nv.w};
#pragma unroll
    for (int r = 0; r < 4; ++r) {
      int kk = k0 + kbase + r;
#pragma unroll
      for (int p = 0; p < PPT; ++p) {
        float d = __fmul_rn(z[p][0], cc[r].x);
        d = __fadd_rn(d, __fmul_rn(z[p][1], cc[r].y));
        d = __fadd_rn(d, __fmul_rn(z[p][2], cc[r].z));
        d = __fadd_rn(d, __fmul_rn(z[p][3], cc[r].w));
        float s = __fadd_rn(__fsub_rn(zz[p], d), cnr[r]);
        if (s < best[p]) { best[p] = s; bidx[p] = kk; }
      }
    }
  };

  // ---- ping-pong chunk loop: 8 codes per iter, no buffer copies ----
  float4 cA[4], nA, cB[4], nB;
  cA[0] = s_c[0]; cA[1] = s_c[1]; cA[2] = s_c[2]; cA[3] = s_c[3];
  nA = *(const float4*)&s_n[0];
  for (int kc = 0; kc < SEGLEN; kc += 8) {
    cB[0] = s_c[kc + 4]; cB[1] = s_c[kc + 5];
    cB[2] = s_c[kc + 6]; cB[3] = s_c[kc + 7];
    nB = *(const float4*)&s_n[kc + 4];
    body(cA, nA, kc);
    int kn = (kc + 8) & (SEGLEN - 1);       // wraps harmlessly on last iter
    cA[0] = s_c[kn + 0]; cA[1] = s_c[kn + 1];
    cA[2] = s_c[kn + 2]; cA[3] = s_c[kn + 3];
    nA = *(const float4*)&s_n[kn];
    body(cB, nB, kc + 4);
  }

#pragma unroll
  for (int p = 0; p < PPT; ++p) {
    // pack (sortable float, k): u64 min == (min value, then min k)
    unsigned int u = __float_as_uint(best[p]);
    unsigned int so = (u & 0x80000000u) ? ~u : (u | 0x80000000u);
    unsigned long long key =
        ((unsigned long long)so << 32) | (unsigned int)bidx[p];
    atomicMin(&packed[n0 + 256 * p], key);
  }
}

// ---------------- Kernel F: decode, gather, latent write, loss -------------
__global__ __launch_bounds__(256) void vq_finish(
    const float* __restrict__ ze, const float* __restrict__ w,
    const float* __restrict__ bias, const float* __restrict__ cb,
    const unsigned long long* __restrict__ packed, float* __restrict__ out) {
  int n = blockIdx.x * 256 + threadIdx.x;
  int bidx = (unsigned int)(packed[n] & 0xFFFFFFFFull);
  float4 c = ((const float4*)cb)[bidx];     // bit-exact gather (16B aligned)
  int b = n >> 12, hw = n & 4095;
  float* o = out + b * CHW + hw;
  o[0] = c.x; o[HW] = c.y; o[2 * HW] = c.z; o[3 * HW] = c.w;
  float z[4], zz;
  compute_z(ze, w, bias, n, z, zz);
  float d0 = c.x - z[0], d1 = c.y - z[1], d2 = c.z - z[2], d3 = c.w - z[3];
  float e = d0 * d0 + d1 * d1 + d2 * d2 + d3 * d3;
#pragma unroll
  for (int off = 32; off > 0; off >>= 1) e += __shfl_down(e, off, 64);
  __shared__ float sred[4];
  if ((threadIdx.x & 63) == 0) sred[threadIdx.x >> 6] = e;
  __syncthreads();
  if (threadIdx.x == 0) {
    float t = (sred[0] + sred[1]) + (sred[2] + sred[3]);
    // q_loss = (1 + BETA) * mean over 131072 elements
    atomicAdd(out + (N_POINTS * 4), t * (1.25f / 131072.f));
  }
}

extern "C" void kernel_launch(void* const* d_in, const int* in_sizes, int n_in,
                              void* d_out, int out_size, void* d_ws, size_t ws_size,
                              hipStream_t stream) {
  const float* ze   = (const float*)d_in[0];  // z_e_in [8,4,64,64]
  const float* w    = (const float*)d_in[1];  // pq_w [4,4]
  const float* bias = (const float*)d_in[2];  // pq_b [4]
  const float* cb   = (const float*)d_in[3];  // codebook [8192,4]

  unsigned long long* packed = (unsigned long long*)((char*)d_ws + WS_PACKED);
  float* out = (float*)d_out;

  // packed := all-ones (atomicMin identity); loss slot := 0
  hipMemsetAsync(packed, 0xFF, (size_t)N_POINTS * 8, stream);
  hipMemsetAsync(out + (N_POINTS * 4), 0, sizeof(float), stream);

  vq_scan<<<dim3(N_POINTS / PTILE, NSEG), 256, 0, stream>>>(
      ze, w, bias, cb, packed);
  vq_finish<<<128, 256, 0, stream>>>(ze, w, bias, cb, packed, out);
}

// Round 12
// 115.792 us; speedup vs baseline: 1.1480x; 1.1480x over previous
//
#include <hip/hip_runtime.h>
#include <math.h>

// Problem constants (fixed by setup_inputs): B=8, C=4, H=W=64, K=8192
#define N_POINTS 32768   // B*H*W
#define KCODES   8192
#define HW       4096
#define CHW      16384
#define NSEG     64
#define SEGLEN   (KCODES / NSEG)   // 128 codes per segment
#define PPT      8                 // points per thread in vq_scan
#define PTILE    (256 * PPT)       // 2048 points per block

// ws layout (bytes):
//   cb2    float4[8192]  @ 0        (2*codebook — exact doubling)
//   cbn    float [8192]  @ 131072   (|c|^2, numpy rounding order; 16B aligned)
//   packed u64   [32768] @ 163840   ((sortable(best_d2)<<32)|best_k per point)
#define WS_CB2    0
#define WS_CBN    131072
#define WS_PACKED 163840

// Bit-exact conv z = W x + b, numpy sequential c-order, no FMA contraction.
__device__ __forceinline__ void compute_z(
    const float* __restrict__ ze, const float* __restrict__ w,
    const float* __restrict__ bias, int n, float zo[4], float& zz) {
  int b = n >> 12, hw = n & 4095;
  const float* p = ze + b * CHW + hw;
  float x0 = p[0], x1 = p[HW], x2 = p[2 * HW], x3 = p[3 * HW];
#pragma unroll
  for (int o = 0; o < 4; ++o) {
    float acc = __fmul_rn(x0, w[o * 4 + 0]);
    acc = __fadd_rn(acc, __fmul_rn(x1, w[o * 4 + 1]));
    acc = __fadd_rn(acc, __fmul_rn(x2, w[o * 4 + 2]));
    acc = __fadd_rn(acc, __fmul_rn(x3, w[o * 4 + 3]));
    zo[o] = __fadd_rn(acc, bias[o]);
  }
  float s = __fmul_rn(zo[0], zo[0]);
  s = __fadd_rn(s, __fmul_rn(zo[1], zo[1]));
  s = __fadd_rn(s, __fmul_rn(zo[2], zo[2]));
  s = __fadd_rn(s, __fmul_rn(zo[3], zo[3]));
  zz = s;
}

// ---------------- Kernel P: init packed + codebook transform + loss zero ---
__global__ __launch_bounds__(256) void vq_init(
    const float* __restrict__ cb, float4* __restrict__ cb2,
    float* __restrict__ cbn, unsigned long long* __restrict__ packed,
    float* __restrict__ out) {
  int t = blockIdx.x * 256 + threadIdx.x;   // grid covers 32768
  packed[t] = 0xFFFFFFFFFFFFFFFFull;        // ws is re-poisoned every call
  if (t < KCODES) {
    float c0 = cb[t * 4 + 0], c1 = cb[t * 4 + 1];
    float c2 = cb[t * 4 + 2], c3 = cb[t * 4 + 3];
    // doubling by 2 is exact: sum(2*z*c) == 2*sum(z*c) bitwise
    cb2[t] = make_float4(2.f * c0, 2.f * c1, 2.f * c2, 2.f * c3);
    float s = __fmul_rn(c0, c0);
    s = __fadd_rn(s, __fmul_rn(c1, c1));
    s = __fadd_rn(s, __fmul_rn(c2, c2));
    s = __fadd_rn(s, __fmul_rn(c3, c3));
    cbn[t] = s;
  }
  if (t == 0) out[N_POINTS * 4] = 0.f;      // zero the q_loss slot
}

// ---------------- Kernel S: fused conv + argmin scan, LDS + reg dbuf -------
// Best-measured formulation (R8: scan 60.4us, 60 VGPR, no spill). Eleven
// rounds of variants (occupancy x2, global/LDS staging, store-vs-atomic,
// packed fp32, unroll restructure) were all neutral or regressions; issue
// time sits at the bit-exact 12-VALU-op/pair floor. Do not restructure:
// the register allocation is on a knife-edge (R11's lambda+unroll -> spills).
__global__ __launch_bounds__(256, 3) void vq_scan(
    const float* __restrict__ ze, const float* __restrict__ w,
    const float* __restrict__ bias, const float4* __restrict__ cb2,
    const float* __restrict__ cbn, unsigned long long* __restrict__ packed) {
  __shared__ float4 s_c[SEGLEN];            // 2*codebook segment (2048 B)
  __shared__ float  s_n[SEGLEN];            // |c|^2 segment (512 B)
  int tid = threadIdx.x;
  int k0 = blockIdx.y * SEGLEN;
  // cooperative stage: 512 dwords of cb2 (2/thread) + 128 dwords of cbn
  ((float*)s_c)[tid]       = ((const float*)(cb2 + k0))[tid];
  ((float*)s_c)[tid + 256] = ((const float*)(cb2 + k0))[tid + 256];
  if (tid < SEGLEN) s_n[tid] = cbn[k0 + tid];
  // conv for this thread's 8 points while the staging loads land
  int n0 = blockIdx.x * PTILE + tid;        // points n0 + 256*p, coalesced
  float z[PPT][4], zz[PPT], best[PPT];
  int bidx[PPT];
#pragma unroll
  for (int p = 0; p < PPT; ++p) {
    compute_z(ze, w, bias, n0 + 256 * p, z[p], zz[p]);
    best[p] = INFINITY;
    bidx[p] = 0;
  }
  __syncthreads();
  // ---- double-buffered chunk loop (4 codes/chunk, ascending k) ----
  float4 cA[4], nA;
  cA[0] = s_c[0]; cA[1] = s_c[1]; cA[2] = s_c[2]; cA[3] = s_c[3];
  nA = *(const float4*)&s_n[0];
  for (int kc = 0; kc < SEGLEN; kc += 4) {
    int kn = (kc + 4) & (SEGLEN - 1);       // wraps harmlessly on last iter
    float4 cB[4], nB;
    cB[0] = s_c[kn + 0]; cB[1] = s_c[kn + 1];
    cB[2] = s_c[kn + 2]; cB[3] = s_c[kn + 3];
    nB = *(const float4*)&s_n[kn];
    float cnr[4] = {nA.x, nA.y, nA.z, nA.w};
#pragma unroll
    for (int r = 0; r < 4; ++r) {
      int kk = k0 + kc + r;                 // ascending k: strict < = first-min
#pragma unroll
      for (int p = 0; p < PPT; ++p) {
        // 2*dot with numpy's sequential rounding order (doubling is exact)
        float d = __fmul_rn(z[p][0], cA[r].x);
        d = __fadd_rn(d, __fmul_rn(z[p][1], cA[r].y));
        d = __fadd_rn(d, __fmul_rn(z[p][2], cA[r].z));
        d = __fadd_rn(d, __fmul_rn(z[p][3], cA[r].w));
        // ref: (|z|^2 - 2*dot) + |c|^2, left-to-right
        float s = __fadd_rn(__fsub_rn(zz[p], d), cnr[r]);
        if (s < best[p]) { best[p] = s; bidx[p] = kk; }
      }
    }
    cA[0] = cB[0]; cA[1] = cB[1]; cA[2] = cB[2]; cA[3] = cB[3];
    nA = nB;
  }
#pragma unroll
  for (int p = 0; p < PPT; ++p) {
    // pack (sortable float, k): u64 min == (min value, then min k)
    unsigned int u = __float_as_uint(best[p]);
    unsigned int so = (u & 0x80000000u) ? ~u : (u | 0x80000000u);
    unsigned long long key =
        ((unsigned long long)so << 32) | (unsigned int)bidx[p];
    atomicMin(&packed[n0 + 256 * p], key);
  }
}

// ---------------- Kernel F: decode, gather, latent write, loss -------------
__global__ __launch_bounds__(256) void vq_finish(
    const float* __restrict__ ze, const float* __restrict__ w,
    const float* __restrict__ bias, const float* __restrict__ cb,
    const unsigned long long* __restrict__ packed, float* __restrict__ out) {
  int n = blockIdx.x * 256 + threadIdx.x;
  int bidx = (unsigned int)(packed[n] & 0xFFFFFFFFull);
  float4 c = ((const float4*)cb)[bidx];     // bit-exact gather (16B aligned)
  int b = n >> 12, hw = n & 4095;
  float* o = out + b * CHW + hw;
  o[0] = c.x; o[HW] = c.y; o[2 * HW] = c.z; o[3 * HW] = c.w;
  float z[4], zz;
  compute_z(ze, w, bias, n, z, zz);
  float d0 = c.x - z[0], d1 = c.y - z[1], d2 = c.z - z[2], d3 = c.w - z[3];
  float e = d0 * d0 + d1 * d1 + d2 * d2 + d3 * d3;
#pragma unroll
  for (int off = 32; off > 0; off >>= 1) e += __shfl_down(e, off, 64);
  __shared__ float sred[4];
  if ((threadIdx.x & 63) == 0) sred[threadIdx.x >> 6] = e;
  __syncthreads();
  if (threadIdx.x == 0) {
    float t = (sred[0] + sred[1]) + (sred[2] + sred[3]);
    // q_loss = (1 + BETA) * mean over 131072 elements
    atomicAdd(out + (N_POINTS * 4), t * (1.25f / 131072.f));
  }
}

extern "C" void kernel_launch(void* const* d_in, const int* in_sizes, int n_in,
                              void* d_out, int out_size, void* d_ws, size_t ws_size,
                              hipStream_t stream) {
  const float* ze   = (const float*)d_in[0];  // z_e_in [8,4,64,64]
  const float* w    = (const float*)d_in[1];  // pq_w [4,4]
  const float* bias = (const float*)d_in[2];  // pq_b [4]
  const float* cb   = (const float*)d_in[3];  // codebook [8192,4]

  char* ws = (char*)d_ws;
  float4* cb2 = (float4*)(ws + WS_CB2);
  float*  cbn = (float*)(ws + WS_CBN);
  unsigned long long* packed = (unsigned long long*)(ws + WS_PACKED);
  float* out = (float*)d_out;

  vq_init<<<128, 256, 0, stream>>>(cb, cb2, cbn, packed, out);
  vq_scan<<<dim3(N_POINTS / PTILE, NSEG), 256, 0, stream>>>(
      ze, w, bias, cb2, cbn, packed);
  vq_finish<<<128, 256, 0, stream>>>(ze, w, bias, cb, packed, out);
}